// Round 6
// baseline (924.211 us; speedup 1.0000x reference)
//
#include <hip/hip_runtime.h>
#include <math.h>

typedef __attribute__((ext_vector_type(4))) float f32x4;
typedef __attribute__((ext_vector_type(2))) unsigned int u32x2;
typedef __attribute__((ext_vector_type(4))) unsigned int u32x4;
typedef __attribute__((ext_vector_type(8))) unsigned short u16x8;
typedef __attribute__((ext_vector_type(8))) __bf16 bf16x8;
typedef unsigned short ushort_t;

#define H_DIM 2048
#define T_TOK 2048
#define NEXP 16
#define I_DIM 1408
#define I2_DIM 2816
#define IS_DIM 5632
#define MAXROWS 8192

static __device__ __forceinline__ unsigned short f2bf(float f){
  union { float f; unsigned u; } v; v.f = f;
  unsigned r = v.u + 0x7FFFu + ((v.u >> 16) & 1u);
  return (unsigned short)(r >> 16);
}
static __device__ __forceinline__ float bf2f(unsigned short h){
  union { unsigned u; float f; } v; v.u = ((unsigned)h) << 16;
  return v.f;
}
static __device__ __forceinline__ float silu_f(float x){ return x / (1.f + __expf(-x)); }

// async global->LDS, 16B/lane; LDS dest wave-uniform base, HW adds lane*16.
static __device__ __forceinline__ void gld16(const ushort_t* g, ushort_t* l){
  __builtin_amdgcn_global_load_lds(
      (const __attribute__((address_space(1))) unsigned int*)g,
      (__attribute__((address_space(3))) unsigned int*)l, 16, 0, 0);
}

// ---------------- cast x -> bf16 ----------------
__global__ void cast_bf16_k(const float* __restrict__ in, ushort_t* __restrict__ out){
  long i = ((long)blockIdx.x * 256 + threadIdx.x) * 8;
  f32x4 a = *(const f32x4*)&in[i];
  f32x4 b = *(const f32x4*)&in[i + 4];
  union { ushort_t s[8]; u32x4 v; } pk;
  #pragma unroll
  for (int j = 0; j < 4; j++){ pk.s[j] = f2bf(a[j]); pk.s[j+4] = f2bf(b[j]); }
  *(u32x4*)&out[i] = pk.v;
}

// ------- transpose + cast: in[z][K][N] fp32 -> out[z][N][K] bf16, 64x64 tiles, 16B I/O -------
__global__ void transpose_cast_k(const float* __restrict__ in, ushort_t* __restrict__ out,
                                 int K, int N){
  long zo = (long)blockIdx.z * K * N;
  in += zo; out += zo;
  __shared__ float tl[64][65];
  int n0 = blockIdx.x * 64, k0 = blockIdx.y * 64;
  int tid = threadIdx.x;           // 256
  int lr = tid >> 2;               // 0..63 source row (k)
  int lv = (tid & 3) * 4;          // vec4 col base
  #pragma unroll
  for (int j = 0; j < 4; j++){
    int col = lv + j * 16;
    f32x4 v = *(const f32x4*)&in[(long)(k0 + lr) * N + n0 + col];
    tl[lr][col + 0] = v[0]; tl[lr][col + 1] = v[1];
    tl[lr][col + 2] = v[2]; tl[lr][col + 3] = v[3];
  }
  __syncthreads();
  int nl = tid >> 3;               // out row (n), 0..31 (+32 second iter)
  int kc = (tid & 7) * 8;          // k group of 8
  #pragma unroll
  for (int it = 0; it < 2; it++){
    int n = nl + it * 32;
    union { ushort_t s[8]; u32x4 v; } pk;
    #pragma unroll
    for (int j = 0; j < 8; j++) pk.s[j] = f2bf(tl[kc + j][n]);
    *(u32x4*)&out[(long)(n0 + n) * K + k0 + kc] = pk.v;
  }
}

// ---------------- router ----------------
__global__ void router_k(const float* __restrict__ x, const float* __restrict__ rw,
                         const float* __restrict__ sgw, float* __restrict__ logits,
                         int* __restrict__ counts, int* __restrict__ lists,
                         float* __restrict__ probs, float* __restrict__ sgmul){
  int wid = threadIdx.x >> 6, lane = threadIdx.x & 63;
  int t = blockIdx.x * 4 + wid;
  const float* xr = x + (long)t * H_DIM;
  float acc[17];
  #pragma unroll
  for (int e = 0; e < 17; e++) acc[e] = 0.f;
  for (int h0 = lane * 4; h0 < H_DIM; h0 += 256){
    f32x4 xv = *(const f32x4*)&xr[h0];
    #pragma unroll
    for (int i = 0; i < 4; i++){
      float xs = xv[i];
      const float* wrow = rw + (long)(h0 + i) * NEXP;
      #pragma unroll
      for (int e = 0; e < 16; e++) acc[e] += xs * wrow[e];
      acc[16] += xs * sgw[h0 + i];
    }
  }
  #pragma unroll
  for (int e = 0; e < 17; e++)
    for (int off = 32; off >= 1; off >>= 1)
      acc[e] += __shfl_xor(acc[e], off);
  if (lane == 0){
    float* lo = logits + (long)t * NEXP;
    #pragma unroll
    for (int e = 0; e < 16; e++) lo[e] = acc[e];
    int e0 = 0;
    #pragma unroll
    for (int e = 1; e < 16; e++) if (acc[e] > acc[e0]) e0 = e;
    int e1 = (e0 == 0) ? 1 : 0;
    #pragma unroll
    for (int e = 0; e < 16; e++) if (e != e0 && acc[e] > acc[e1]) e1 = e;
    float d = acc[e1] - acc[e0];
    float ed = __expf(d);
    float p0 = 1.f / (1.f + ed);
    float p1 = ed / (1.f + ed);
    int pos0 = atomicAdd(&counts[e0], 1);
    lists[e0 * T_TOK + pos0] = t; probs[e0 * T_TOK + pos0] = p0;
    int pos1 = atomicAdd(&counts[e1], 1);
    lists[e1 * T_TOK + pos1] = t; probs[e1 * T_TOK + pos1] = p1;
    sgmul[t] = 1.f / (1.f + __expf(-acc[16]));
  }
}

// ---------------- padded prefix bases (256-aligned) ----------------
__global__ void bases_k(const int* __restrict__ counts, int* __restrict__ bases){
  if (threadIdx.x == 0){
    int r = 0;
    for (int e = 0; e < NEXP; e++){ bases[e] = r; r += (counts[e] + 255) & ~255; }
  }
}

// ---------------- SwiGLU elementwise ----------------
__global__ void swiglu_expert_k(const ushort_t* __restrict__ gu, ushort_t* __restrict__ hid){
  long qd = (long)blockIdx.x * 256 + threadIdx.x;
  long r = qd / (I_DIM / 8); int ic = (int)(qd % (I_DIM / 8)) * 8;
  const ushort_t* g = gu + r * I2_DIM + ic;
  u16x8 gv = *(const u16x8*)g;
  u16x8 uv = *(const u16x8*)(g + I_DIM);
  u16x8 ov;
  #pragma unroll
  for (int i = 0; i < 8; i++)
    ov[i] = f2bf(bf2f(uv[i]) * silu_f(bf2f(gv[i])));
  *(u16x8*)&hid[r * I_DIM + ic] = ov;
}

__global__ void swiglu_flat_k(ushort_t* __restrict__ sg, const ushort_t* __restrict__ si){
  long i = ((long)blockIdx.x * 256 + threadIdx.x) * 8;
  u16x8 g = *(const u16x8*)&sg[i];
  u16x8 s = *(const u16x8*)&si[i];
  u16x8 o;
  #pragma unroll
  for (int j = 0; j < 8; j++)
    o[j] = f2bf(bf2f(s[j]) * silu_f(bf2f(g[j])));
  *(u16x8*)&sg[i] = o;
}

// ============ 256x256 / BK=64 / 8-wave 2-phase GEMM ============
// Key ordering (R6): ALL current-tile ds_reads -> sched_barrier -> prefetch gld16 -> MFMA -> barrier.
// No ds_read may follow an outstanding gld16 (alias -> compiler vmcnt(0) drain kills overlap).
template<int MODE>
__global__ __launch_bounds__(512, 2)
void gemm2_k(const ushort_t* __restrict__ A, const ushort_t* __restrict__ Bt,
             const ushort_t* __restrict__ Bt2, ushort_t* __restrict__ Cb,
             int K, int lda, int ldbt, int ldc, int mb,
             const int* __restrict__ counts, const int* __restrict__ bases,
             const int* __restrict__ lists, const float* __restrict__ probs,
             const float* __restrict__ svec, float* __restrict__ outp,
             long bstride){
  int z = blockIdx.z;
  int cnt = T_TOK;
  const ushort_t* Ab = A;
  const ushort_t* Bb = Bt;
  long rbase = 0;
  if constexpr (MODE == 0){ if (z){ Bb = Bt2; Cb += (long)T_TOK * ldc; } }
  if constexpr (MODE == 1){ cnt = counts[z]; rbase = bases[z]; Bb += (long)z * bstride; }
  if constexpr (MODE == 2){ cnt = counts[z]; Ab += (long)bases[z] * lda; Bb += (long)z * bstride; }

  int kb = K / gridDim.y;
  int kbase = blockIdx.y * kb;
  Ab += kbase;
  Bb += kbase;

  // bijective XCD-chunked swizzle (m204)
  int nwg = gridDim.x;
  int wgo = blockIdx.x;
  int q = nwg >> 3, r = nwg & 7;
  int xcd = wgo & 7, idx = wgo >> 3;
  int wg = (xcd < r ? xcd * (q + 1) : r * (q + 1) + (xcd - r) * q) + idx;
  int m0 = (wg % mb) * 256;
  if (m0 >= cnt) return;
  int n0 = (wg / mb) * 256;

  extern __shared__ ushort_t lds[];   // [2 buf][A 16K elems | B 16K elems] = 128 KiB

  int tid = threadIdx.x;
  int lane = tid & 63;
  int wv = tid >> 6;
  int wm = wv >> 2;
  int wn = wv & 3;

  // staging: wave stages rows [wv*32, wv*32+32) of A and Bt, 4 gld16 each.
  // lane -> row += lane>>3, global slot pre-swizzled: (lane&7)^(lane>>3).
  int sg = ((lane & 7) ^ (lane >> 3)) * 8;
  long aoff0, boff0;
  long aoffg[4];
  {
    int r0 = wv * 32 + (lane >> 3);
    if constexpr (MODE == 1){
      #pragma unroll
      for (int i = 0; i < 4; i++){
        int j = m0 + r0 + i * 8; if (j >= cnt) j = cnt - 1;
        aoffg[i] = (long)lists[z * T_TOK + j] * lda + sg;
      }
    } else {
      aoff0 = (long)(m0 + r0) * lda + sg;
    }
    boff0 = (long)(n0 + r0) * ldbt + sg;
  }

  auto stage = [&](long ko, int buf){
    ushort_t* dA = lds + buf * 32768 + wv * 32 * 64;
    ushort_t* dB = dA + 16384;
    #pragma unroll
    for (int i = 0; i < 4; i++){
      long ao;
      if constexpr (MODE == 1) ao = aoffg[i]; else ao = aoff0 + (long)(i * 8) * lda;
      gld16(Ab + ao + ko, dA + i * 512);
    }
    #pragma unroll
    for (int i = 0; i < 4; i++)
      gld16(Bb + boff0 + (long)(i * 8) * ldbt + ko, dB + i * 512);
  };

  f32x4 zero = {0.f, 0.f, 0.f, 0.f};
  f32x4 acc[8][4];
  #pragma unroll
  for (int i = 0; i < 8; i++)
    #pragma unroll
    for (int j = 0; j < 4; j++) acc[i][j] = zero;

  int nt = kb >> 6;
  stage(0, 0);
  __syncthreads();

  for (int t = 0; t < nt; t++){
    int c = t & 1;
    const ushort_t* tA = lds + c * 32768;
    const ushort_t* tB = tA + 16384;
    bf16x8 af[2][8], bf[2][4];
    #pragma unroll
    for (int kk = 0; kk < 2; kk++){
      int cs = ((kk * 4 + (lane >> 4)) ^ (lane & 7)) * 8;
      #pragma unroll
      for (int fm = 0; fm < 8; fm++)
        af[kk][fm] = *(const bf16x8*)&tA[(wm*128 + fm*16 + (lane & 15)) * 64 + cs];
      #pragma unroll
      for (int fn = 0; fn < 4; fn++)
        bf[kk][fn] = *(const bf16x8*)&tB[(wn*64 + fn*16 + (lane & 15)) * 64 + cs];
    }
    __builtin_amdgcn_sched_barrier(0);   // no gld16 may hoist above the ds_reads
    if (t + 1 < nt) stage((long)(t + 1) * 64, c ^ 1);
    #pragma unroll
    for (int kk = 0; kk < 2; kk++)
      #pragma unroll
      for (int fm = 0; fm < 8; fm++)
        #pragma unroll
        for (int fn = 0; fn < 4; fn++)
          acc[fm][fn] = __builtin_amdgcn_mfma_f32_16x16x32_bf16(af[kk][fm], bf[kk][fn], acc[fm][fn], 0, 0, 0);
    __syncthreads();   // drains vmcnt(0): prefetched buf published; readers done with buf c
  }

  int colb = n0 + wn * 64 + (lane & 15);
  int rowb = m0 + wm * 128 + (lane >> 4) * 4;
  #pragma unroll
  for (int fm = 0; fm < 8; fm++){
    #pragma unroll
    for (int fn = 0; fn < 4; fn++){
      f32x4 v = acc[fm][fn];
      int col = colb + fn * 16;
      #pragma unroll
      for (int rr = 0; rr < 4; rr++){
        int m = rowb + fm * 16 + rr;
        if constexpr (MODE == 0){
          Cb[(long)m * ldc + col] = f2bf(v[rr]);
        } else if constexpr (MODE == 1){
          if (m < cnt) Cb[(rbase + m) * (long)ldc + col] = f2bf(v[rr]);
        } else if constexpr (MODE == 2){
          if (m < cnt){
            int tok = lists[z * T_TOK + m];
            float pp = probs[z * T_TOK + m];
            atomicAdd(outp + (long)tok * ldc + col, pp * v[rr]);
          }
        } else {
          atomicAdd(outp + (long)m * ldc + col, svec[m] * v[rr]);
        }
      }
    }
  }
}

extern "C" void kernel_launch(void* const* d_in, const int* in_sizes, int n_in,
                              void* d_out, int out_size, void* d_ws, size_t ws_size,
                              hipStream_t stream){
  const float* x    = (const float*)d_in[0];
  const float* rw   = (const float*)d_in[1];
  const float* wgu  = (const float*)d_in[2];
  const float* wout = (const float*)d_in[3];
  const float* wsg  = (const float*)d_in[4];
  const float* wsi  = (const float*)d_in[5];
  const float* wso  = (const float*)d_in[6];
  const float* sgw  = (const float*)d_in[7];

  float* out = (float*)d_out;
  float* logits = out + (size_t)T_TOK * H_DIM;

  char* w = (char*)d_ws;
  auto alloc = [&](size_t b){ char* p = w; w += (b + 255) & ~(size_t)255; return p; };
  ushort_t* xb     = (ushort_t*)alloc((size_t)T_TOK * H_DIM * 2);
  ushort_t* wgu_t  = (ushort_t*)alloc((size_t)NEXP * I2_DIM * H_DIM * 2);
  ushort_t* wout_t = (ushort_t*)alloc((size_t)NEXP * H_DIM * I_DIM * 2);
  ushort_t* wsg_t  = (ushort_t*)alloc((size_t)IS_DIM * H_DIM * 2);
  ushort_t* wsi_t  = (ushort_t*)alloc((size_t)IS_DIM * H_DIM * 2);
  ushort_t* wso_t  = (ushort_t*)alloc((size_t)H_DIM * IS_DIM * 2);
  ushort_t* sgr    = (ushort_t*)alloc((size_t)2 * T_TOK * IS_DIM * 2);
  ushort_t* sir    = sgr + (size_t)T_TOK * IS_DIM;
  ushort_t* gu     = (ushort_t*)alloc((size_t)MAXROWS * I2_DIM * 2);
  ushort_t* hid    = (ushort_t*)alloc((size_t)MAXROWS * I_DIM * 2);
  int*   counts = (int*)alloc(64);
  int*   bases  = (int*)alloc(64);
  int*   lists  = (int*)alloc((size_t)NEXP * T_TOK * 4);
  float* probs  = (float*)alloc((size_t)NEXP * T_TOK * 4);
  float* sgmul  = (float*)alloc((size_t)T_TOK * 4);

  hipMemsetAsync(counts, 0, 64, stream);
  hipMemsetAsync(out, 0, (size_t)T_TOK * H_DIM * sizeof(float), stream);

  cast_bf16_k<<<2048, 256, 0, stream>>>(x, xb);
  transpose_cast_k<<<dim3(I2_DIM/64, H_DIM/64, NEXP), 256, 0, stream>>>(wgu, wgu_t, H_DIM, I2_DIM);
  transpose_cast_k<<<dim3(H_DIM/64, I_DIM/64, NEXP), 256, 0, stream>>>(wout, wout_t, I_DIM, H_DIM);
  transpose_cast_k<<<dim3(IS_DIM/64, H_DIM/64, 1), 256, 0, stream>>>(wsg, wsg_t, H_DIM, IS_DIM);
  transpose_cast_k<<<dim3(IS_DIM/64, H_DIM/64, 1), 256, 0, stream>>>(wsi, wsi_t, H_DIM, IS_DIM);
  transpose_cast_k<<<dim3(H_DIM/64, IS_DIM/64, 1), 256, 0, stream>>>(wso, wso_t, IS_DIM, H_DIM);

  router_k<<<512, 256, 0, stream>>>(x, rw, sgw, logits, counts, lists, probs, sgmul);
  bases_k<<<1, 64, 0, stream>>>(counts, bases);

  const size_t LDSB = 2 * 2 * 256 * 64 * sizeof(ushort_t);  // 128 KiB

  gemm2_k<0><<<dim3((T_TOK/256) * (IS_DIM/256), 1, 2), 512, LDSB, stream>>>(
      xb, wsg_t, wsi_t, sgr, H_DIM, H_DIM, H_DIM, IS_DIM, T_TOK/256,
      nullptr, nullptr, nullptr, nullptr, nullptr, nullptr, 0);
  swiglu_flat_k<<<(T_TOK * (IS_DIM/8)) / 256, 256, 0, stream>>>(sgr, sir);
  gemm2_k<3><<<dim3((T_TOK/256) * (H_DIM/256), 4, 1), 512, LDSB, stream>>>(
      sgr, wso_t, nullptr, nullptr, IS_DIM, IS_DIM, IS_DIM, H_DIM, T_TOK/256,
      nullptr, nullptr, nullptr, nullptr, sgmul, out, 0);

  gemm2_k<1><<<dim3((T_TOK/256) * (I2_DIM/256), 1, NEXP), 512, LDSB, stream>>>(
      xb, wgu_t, nullptr, gu, H_DIM, H_DIM, H_DIM, I2_DIM, T_TOK/256,
      counts, bases, lists, probs, nullptr, nullptr, (long)I2_DIM * H_DIM);
  swiglu_expert_k<<<((long)MAXROWS * (I_DIM/8)) / 256, 256, 0, stream>>>(gu, hid);
  gemm2_k<2><<<dim3((T_TOK/256) * (H_DIM/256), 1, NEXP), 512, LDSB, stream>>>(
      hid, wout_t, nullptr, nullptr, I_DIM, I_DIM, I_DIM, H_DIM, T_TOK/256,
      counts, bases, lists, probs, nullptr, out, (long)I_DIM * H_DIM);

  (void)in_sizes; (void)n_in; (void)out_size; (void)ws_size;
}

// Round 7
// 848.624 us; speedup vs baseline: 1.0891x; 1.0891x over previous
//
#include <hip/hip_runtime.h>
#include <math.h>

typedef __attribute__((ext_vector_type(4))) float f32x4;
typedef __attribute__((ext_vector_type(2))) unsigned int u32x2;
typedef __attribute__((ext_vector_type(4))) unsigned int u32x4;
typedef __attribute__((ext_vector_type(8))) unsigned short u16x8;
typedef __attribute__((ext_vector_type(8))) __bf16 bf16x8;
typedef unsigned short ushort_t;

#define H_DIM 2048
#define T_TOK 2048
#define NEXP 16
#define I_DIM 1408
#define I2_DIM 2816
#define IS_DIM 5632
#define MAXROWS 8192

static __device__ __forceinline__ unsigned short f2bf(float f){
  union { float f; unsigned u; } v; v.f = f;
  unsigned r = v.u + 0x7FFFu + ((v.u >> 16) & 1u);
  return (unsigned short)(r >> 16);
}
static __device__ __forceinline__ float bf2f(unsigned short h){
  union { unsigned u; float f; } v; v.u = ((unsigned)h) << 16;
  return v.f;
}
static __device__ __forceinline__ float silu_f(float x){ return x / (1.f + __expf(-x)); }

// async global->LDS, 16B/lane; LDS dest wave-uniform base, HW adds lane*16.
static __device__ __forceinline__ void gld16(const ushort_t* g, ushort_t* l){
  __builtin_amdgcn_global_load_lds(
      (const __attribute__((address_space(1))) unsigned int*)g,
      (__attribute__((address_space(3))) unsigned int*)l, 16, 0, 0);
}

// ---------------- cast x -> bf16 ----------------
__global__ void cast_bf16_k(const float* __restrict__ in, ushort_t* __restrict__ out){
  long i = ((long)blockIdx.x * 256 + threadIdx.x) * 8;
  f32x4 a = *(const f32x4*)&in[i];
  f32x4 b = *(const f32x4*)&in[i + 4];
  union { ushort_t s[8]; u32x4 v; } pk;
  #pragma unroll
  for (int j = 0; j < 4; j++){ pk.s[j] = f2bf(a[j]); pk.s[j+4] = f2bf(b[j]); }
  *(u32x4*)&out[i] = pk.v;
}

// ------- transpose + cast: in[z][K][N] fp32 -> out[z][N][K] bf16, 64x64 tiles, 16B I/O -------
__global__ void transpose_cast_k(const float* __restrict__ in, ushort_t* __restrict__ out,
                                 int K, int N){
  long zo = (long)blockIdx.z * K * N;
  in += zo; out += zo;
  __shared__ float tl[64][65];
  int n0 = blockIdx.x * 64, k0 = blockIdx.y * 64;
  int tid = threadIdx.x;           // 256
  int lr = tid >> 2;               // 0..63 source row (k)
  int lv = (tid & 3) * 4;          // vec4 col base
  #pragma unroll
  for (int j = 0; j < 4; j++){
    int col = lv + j * 16;
    f32x4 v = *(const f32x4*)&in[(long)(k0 + lr) * N + n0 + col];
    tl[lr][col + 0] = v[0]; tl[lr][col + 1] = v[1];
    tl[lr][col + 2] = v[2]; tl[lr][col + 3] = v[3];
  }
  __syncthreads();
  int nl = tid >> 3;               // out row (n)
  int kc = (tid & 7) * 8;          // k group of 8
  #pragma unroll
  for (int it = 0; it < 2; it++){
    int n = nl + it * 32;
    union { ushort_t s[8]; u32x4 v; } pk;
    #pragma unroll
    for (int j = 0; j < 8; j++) pk.s[j] = f2bf(tl[kc + j][n]);
    *(u32x4*)&out[(long)(n0 + n) * K + k0 + kc] = pk.v;
  }
}

// ---------------- router ----------------
__global__ void router_k(const float* __restrict__ x, const float* __restrict__ rw,
                         const float* __restrict__ sgw, float* __restrict__ logits,
                         int* __restrict__ counts, int* __restrict__ lists,
                         float* __restrict__ probs, float* __restrict__ sgmul){
  int wid = threadIdx.x >> 6, lane = threadIdx.x & 63;
  int t = blockIdx.x * 4 + wid;
  const float* xr = x + (long)t * H_DIM;
  float acc[17];
  #pragma unroll
  for (int e = 0; e < 17; e++) acc[e] = 0.f;
  for (int h0 = lane * 4; h0 < H_DIM; h0 += 256){
    f32x4 xv = *(const f32x4*)&xr[h0];
    #pragma unroll
    for (int i = 0; i < 4; i++){
      float xs = xv[i];
      const float* wrow = rw + (long)(h0 + i) * NEXP;
      #pragma unroll
      for (int e = 0; e < 16; e++) acc[e] += xs * wrow[e];
      acc[16] += xs * sgw[h0 + i];
    }
  }
  #pragma unroll
  for (int e = 0; e < 17; e++)
    for (int off = 32; off >= 1; off >>= 1)
      acc[e] += __shfl_xor(acc[e], off);
  if (lane == 0){
    float* lo = logits + (long)t * NEXP;
    #pragma unroll
    for (int e = 0; e < 16; e++) lo[e] = acc[e];
    int e0 = 0;
    #pragma unroll
    for (int e = 1; e < 16; e++) if (acc[e] > acc[e0]) e0 = e;
    int e1 = (e0 == 0) ? 1 : 0;
    #pragma unroll
    for (int e = 0; e < 16; e++) if (e != e0 && acc[e] > acc[e1]) e1 = e;
    float d = acc[e1] - acc[e0];
    float ed = __expf(d);
    float p0 = 1.f / (1.f + ed);
    float p1 = ed / (1.f + ed);
    int pos0 = atomicAdd(&counts[e0], 1);
    lists[e0 * T_TOK + pos0] = t; probs[e0 * T_TOK + pos0] = p0;
    int pos1 = atomicAdd(&counts[e1], 1);
    lists[e1 * T_TOK + pos1] = t; probs[e1 * T_TOK + pos1] = p1;
    sgmul[t] = 1.f / (1.f + __expf(-acc[16]));
  }
}

// ---------------- padded prefix bases (256-aligned) ----------------
__global__ void bases_k(const int* __restrict__ counts, int* __restrict__ bases){
  if (threadIdx.x == 0){
    int r = 0;
    for (int e = 0; e < NEXP; e++){ bases[e] = r; r += (counts[e] + 255) & ~255; }
  }
}

// ---------------- SwiGLU elementwise ----------------
__global__ void swiglu_expert_k(const ushort_t* __restrict__ gu, ushort_t* __restrict__ hid){
  long qd = (long)blockIdx.x * 256 + threadIdx.x;
  long r = qd / (I_DIM / 8); int ic = (int)(qd % (I_DIM / 8)) * 8;
  const ushort_t* g = gu + r * I2_DIM + ic;
  u16x8 gv = *(const u16x8*)g;
  u16x8 uv = *(const u16x8*)(g + I_DIM);
  u16x8 ov;
  #pragma unroll
  for (int i = 0; i < 8; i++)
    ov[i] = f2bf(bf2f(uv[i]) * silu_f(bf2f(gv[i])));
  *(u16x8*)&hid[r * I_DIM + ic] = ov;
}

__global__ void swiglu_flat_k(ushort_t* __restrict__ sg, const ushort_t* __restrict__ si){
  long i = ((long)blockIdx.x * 256 + threadIdx.x) * 8;
  u16x8 g = *(const u16x8*)&sg[i];
  u16x8 s = *(const u16x8*)&si[i];
  u16x8 o;
  #pragma unroll
  for (int j = 0; j < 8; j++)
    o[j] = f2bf(bf2f(s[j]) * silu_f(bf2f(g[j])));
  *(u16x8*)&sg[i] = o;
}

// ============ 256(M) x 128(N) x 64(K) GEMM, 8 waves (4x2), 3-buffer counted-vmcnt pipeline ====
// Pipeline: stage tile t+2 into buf (t+2)%3 while computing tile t from buf t%3.
// Top of iter t: s_waitcnt vmcnt(6) (own 6 gld16 of tile t done; t+1's 6 may fly) -> s_barrier
// (all waves' tile-t stages landed; all waves done reading buf (t-1)%3 which t+2 overwrites).
// NO vmcnt(0) drain in the main loop (T4, m218).
template<int MODE>
__global__ __launch_bounds__(512, 2)
void gemm2_k(const ushort_t* __restrict__ A, const ushort_t* __restrict__ Bt,
             const ushort_t* __restrict__ Bt2, ushort_t* __restrict__ Cb,
             int K, int lda, int ldbt, int ldc, int mb,
             const int* __restrict__ counts, const int* __restrict__ bases,
             const int* __restrict__ lists, const float* __restrict__ probs,
             const float* __restrict__ svec, float* __restrict__ outp,
             long bstride){
  int z = blockIdx.z;
  int cnt = T_TOK;
  const ushort_t* Ab = A;
  const ushort_t* Bb = Bt;
  long rbase = 0;
  if constexpr (MODE == 0){ if (z){ Bb = Bt2; Cb += (long)T_TOK * ldc; } }
  if constexpr (MODE == 1){ cnt = counts[z]; rbase = bases[z]; Bb += (long)z * bstride; }
  if constexpr (MODE == 2){ cnt = counts[z]; Ab += (long)bases[z] * lda; Bb += (long)z * bstride; }

  int kb = K / gridDim.y;
  int kbase = blockIdx.y * kb;
  Ab += kbase;
  Bb += kbase;   // Bt is [N][K], k fastest

  // bijective XCD-chunked swizzle (m204)
  int nwg = gridDim.x;
  int wgo = blockIdx.x;
  int q = nwg >> 3, r = nwg & 7;
  int xcd = wgo & 7, idx = wgo >> 3;
  int wg = (xcd < r ? xcd * (q + 1) : r * (q + 1) + (xcd - r) * q) + idx;
  int m0 = (wg % mb) * 256;
  if (m0 >= cnt) return;
  int n0 = (wg / mb) * 128;

  extern __shared__ ushort_t lds[];   // 3 bufs x (A 16384 + B 8192) elems = 144 KiB

  int tid = threadIdx.x;
  int lane = tid & 63;
  int wv = tid >> 6;        // 8 waves
  int wm = wv >> 1;         // 0..3 -> 64 rows each
  int wn = wv & 1;          // 0..1 -> 64 cols each

  // staging: per tile, wave wv stages A rows [wv*32, +32) (4 gld16) and B rows [wv*16, +16)
  // (2 gld16). lane: row += lane>>3, global slot pre-swizzled (lane&7)^(lane>>3).
  int sg = ((lane & 7) ^ (lane >> 3)) * 8;
  long aoff0 = 0, boff0;
  long aoffg[4];
  {
    int r0 = lane >> 3;
    if constexpr (MODE == 1){
      #pragma unroll
      for (int j = 0; j < 4; j++){
        int jj = m0 + wv * 32 + j * 8 + r0; if (jj >= cnt) jj = cnt - 1;
        aoffg[j] = (long)lists[z * T_TOK + jj] * lda + sg;
      }
    } else {
      aoff0 = (long)(m0 + wv * 32 + r0) * lda + sg;
    }
    boff0 = (long)(n0 + wv * 16 + r0) * ldbt + sg;
  }

  auto stage = [&](int t, int buf){
    long ko = (long)t * 64;
    ushort_t* dA = lds + buf * 24576 + (wv * 32) * 64;
    ushort_t* dB = lds + buf * 24576 + 16384 + (wv * 16) * 64;
    #pragma unroll
    for (int j = 0; j < 4; j++){
      long ao;
      if constexpr (MODE == 1) ao = aoffg[j]; else ao = aoff0 + (long)(j * 8) * lda;
      gld16(Ab + ao + ko, dA + j * 512);
    }
    #pragma unroll
    for (int j = 0; j < 2; j++)
      gld16(Bb + boff0 + (long)(j * 8) * ldbt + ko, dB + j * 512);
  };

  f32x4 zero = {0.f, 0.f, 0.f, 0.f};
  f32x4 acc[4][4];
  #pragma unroll
  for (int i = 0; i < 4; i++)
    #pragma unroll
    for (int j = 0; j < 4; j++) acc[i][j] = zero;

  int nt = kb >> 6;
  stage(0, 0);
  __builtin_amdgcn_sched_barrier(0);   // keep stage(0)'s issue group before stage(1)'s
  stage(1, 1);

  int rb = 0, sb = 2;
  for (int t = 0; t < nt; t++){
    if (t + 1 < nt) asm volatile("s_waitcnt vmcnt(6)" ::: "memory");
    else            asm volatile("s_waitcnt vmcnt(0)" ::: "memory");
    __builtin_amdgcn_s_barrier();
    __builtin_amdgcn_sched_barrier(0); // reads must not hoist above barrier/wait
    const ushort_t* tA = lds + rb * 24576;
    const ushort_t* tB = tA + 16384;
    bf16x8 af[2][4], bg[2][4];
    #pragma unroll
    for (int kk = 0; kk < 2; kk++){
      int cs = ((kk * 4 + (lane >> 4)) ^ (lane & 7)) * 8;
      #pragma unroll
      for (int f = 0; f < 4; f++){
        af[kk][f] = *(const bf16x8*)&tA[(wm*64 + f*16 + (lane & 15)) * 64 + cs];
        bg[kk][f] = *(const bf16x8*)&tB[(wn*64 + f*16 + (lane & 15)) * 64 + cs];
      }
    }
    __builtin_amdgcn_sched_barrier(0); // gld16 of t+2 must not hoist above the reads
    if (t + 2 < nt) stage(t + 2, sb);
    #pragma unroll
    for (int kk = 0; kk < 2; kk++)
      #pragma unroll
      for (int fm = 0; fm < 4; fm++)
        #pragma unroll
        for (int fn = 0; fn < 4; fn++)
          acc[fm][fn] = __builtin_amdgcn_mfma_f32_16x16x32_bf16(af[kk][fm], bg[kk][fn], acc[fm][fn], 0, 0, 0);
    rb = (rb == 2) ? 0 : rb + 1;
    sb = (sb == 2) ? 0 : sb + 1;
  }

  int colb = n0 + wn * 64 + (lane & 15);
  int rowb = m0 + wm * 64 + (lane >> 4) * 4;
  #pragma unroll
  for (int fm = 0; fm < 4; fm++){
    #pragma unroll
    for (int fn = 0; fn < 4; fn++){
      f32x4 v = acc[fm][fn];
      int col = colb + fn * 16;
      #pragma unroll
      for (int rr = 0; rr < 4; rr++){
        int m = rowb + fm * 16 + rr;
        if constexpr (MODE == 0){
          Cb[(long)m * ldc + col] = f2bf(v[rr]);
        } else if constexpr (MODE == 1){
          if (m < cnt) Cb[(rbase + m) * (long)ldc + col] = f2bf(v[rr]);
        } else if constexpr (MODE == 2){
          if (m < cnt){
            int tok = lists[z * T_TOK + m];
            float pp = probs[z * T_TOK + m];
            atomicAdd(outp + (long)tok * ldc + col, pp * v[rr]);
          }
        } else {
          atomicAdd(outp + (long)m * ldc + col, svec[m] * v[rr]);
        }
      }
    }
  }
}

extern "C" void kernel_launch(void* const* d_in, const int* in_sizes, int n_in,
                              void* d_out, int out_size, void* d_ws, size_t ws_size,
                              hipStream_t stream){
  const float* x    = (const float*)d_in[0];
  const float* rw   = (const float*)d_in[1];
  const float* wgu  = (const float*)d_in[2];
  const float* wout = (const float*)d_in[3];
  const float* wsg  = (const float*)d_in[4];
  const float* wsi  = (const float*)d_in[5];
  const float* wso  = (const float*)d_in[6];
  const float* sgw  = (const float*)d_in[7];

  float* out = (float*)d_out;
  float* logits = out + (size_t)T_TOK * H_DIM;

  char* w = (char*)d_ws;
  auto alloc = [&](size_t b){ char* p = w; w += (b + 255) & ~(size_t)255; return p; };
  ushort_t* xb     = (ushort_t*)alloc((size_t)T_TOK * H_DIM * 2);
  ushort_t* wgu_t  = (ushort_t*)alloc((size_t)NEXP * I2_DIM * H_DIM * 2);
  ushort_t* wout_t = (ushort_t*)alloc((size_t)NEXP * H_DIM * I_DIM * 2);
  ushort_t* wsg_t  = (ushort_t*)alloc((size_t)IS_DIM * H_DIM * 2);
  ushort_t* wsi_t  = (ushort_t*)alloc((size_t)IS_DIM * H_DIM * 2);
  ushort_t* wso_t  = (ushort_t*)alloc((size_t)H_DIM * IS_DIM * 2);
  ushort_t* sgr    = (ushort_t*)alloc((size_t)2 * T_TOK * IS_DIM * 2);
  ushort_t* sir    = sgr + (size_t)T_TOK * IS_DIM;
  ushort_t* gu     = (ushort_t*)alloc((size_t)MAXROWS * I2_DIM * 2);
  ushort_t* hid    = (ushort_t*)alloc((size_t)MAXROWS * I_DIM * 2);
  int*   counts = (int*)alloc(64);
  int*   bases  = (int*)alloc(64);
  int*   lists  = (int*)alloc((size_t)NEXP * T_TOK * 4);
  float* probs  = (float*)alloc((size_t)NEXP * T_TOK * 4);
  float* sgmul  = (float*)alloc((size_t)T_TOK * 4);

  hipMemsetAsync(counts, 0, 64, stream);
  hipMemsetAsync(out, 0, (size_t)T_TOK * H_DIM * sizeof(float), stream);

  cast_bf16_k<<<2048, 256, 0, stream>>>(x, xb);
  transpose_cast_k<<<dim3(I2_DIM/64, H_DIM/64, NEXP), 256, 0, stream>>>(wgu, wgu_t, H_DIM, I2_DIM);
  transpose_cast_k<<<dim3(H_DIM/64, I_DIM/64, NEXP), 256, 0, stream>>>(wout, wout_t, I_DIM, H_DIM);
  transpose_cast_k<<<dim3(IS_DIM/64, H_DIM/64, 1), 256, 0, stream>>>(wsg, wsg_t, H_DIM, IS_DIM);
  transpose_cast_k<<<dim3(IS_DIM/64, H_DIM/64, 1), 256, 0, stream>>>(wsi, wsi_t, H_DIM, IS_DIM);
  transpose_cast_k<<<dim3(H_DIM/64, IS_DIM/64, 1), 256, 0, stream>>>(wso, wso_t, IS_DIM, H_DIM);

  router_k<<<512, 256, 0, stream>>>(x, rw, sgw, logits, counts, lists, probs, sgmul);
  bases_k<<<1, 64, 0, stream>>>(counts, bases);

  const size_t LDSB = 3 * 24576 * sizeof(ushort_t);  // 144 KiB

  gemm2_k<0><<<dim3((T_TOK/256) * (IS_DIM/128), 1, 2), 512, LDSB, stream>>>(
      xb, wsg_t, wsi_t, sgr, H_DIM, H_DIM, H_DIM, IS_DIM, T_TOK/256,
      nullptr, nullptr, nullptr, nullptr, nullptr, nullptr, 0);
  swiglu_flat_k<<<(T_TOK * (IS_DIM/8)) / 256, 256, 0, stream>>>(sgr, sir);
  gemm2_k<3><<<dim3((T_TOK/256) * (H_DIM/128), 4, 1), 512, LDSB, stream>>>(
      sgr, wso_t, nullptr, nullptr, IS_DIM, IS_DIM, IS_DIM, H_DIM, T_TOK/256,
      nullptr, nullptr, nullptr, nullptr, sgmul, out, 0);

  gemm2_k<1><<<dim3((T_TOK/256) * (I2_DIM/128), 1, NEXP), 512, LDSB, stream>>>(
      xb, wgu_t, nullptr, gu, H_DIM, H_DIM, H_DIM, I2_DIM, T_TOK/256,
      counts, bases, lists, probs, nullptr, nullptr, (long)I2_DIM * H_DIM);
  swiglu_expert_k<<<((long)MAXROWS * (I_DIM/8)) / 256, 256, 0, stream>>>(gu, hid);
  gemm2_k<2><<<dim3((T_TOK/256) * (H_DIM/128), 1, NEXP), 512, LDSB, stream>>>(
      hid, wout_t, nullptr, nullptr, I_DIM, I_DIM, I_DIM, H_DIM, T_TOK/256,
      counts, bases, lists, probs, nullptr, out, (long)I_DIM * H_DIM);

  (void)in_sizes; (void)n_in; (void)out_size; (void)ws_size;
}

// Round 8
// 798.948 us; speedup vs baseline: 1.1568x; 1.0622x over previous
//
#include <hip/hip_runtime.h>
#include <math.h>

typedef __attribute__((ext_vector_type(4))) float f32x4;
typedef __attribute__((ext_vector_type(4))) unsigned int u32x4;
typedef __attribute__((ext_vector_type(8))) unsigned short u16x8;
typedef __attribute__((ext_vector_type(8))) __bf16 bf16x8;
typedef unsigned short ushort_t;

#define H_DIM 2048
#define T_TOK 2048
#define NEXP 16
#define I_DIM 1408
#define I2_DIM 2816
#define IS_DIM 5632
#define MAXROWS 8192

static __device__ __forceinline__ unsigned short f2bf(float f){
  union { float f; unsigned u; } v; v.f = f;
  unsigned r = v.u + 0x7FFFu + ((v.u >> 16) & 1u);
  return (unsigned short)(r >> 16);
}
static __device__ __forceinline__ float bf2f(unsigned short h){
  union { unsigned u; float f; } v; v.u = ((unsigned)h) << 16;
  return v.f;
}
static __device__ __forceinline__ float silu_f(float x){ return x / (1.f + __expf(-x)); }

// async global->LDS, 16B/lane; LDS dest wave-uniform base, HW adds lane*16.
static __device__ __forceinline__ void gld16(const ushort_t* g, ushort_t* l){
  __builtin_amdgcn_global_load_lds(
      (const __attribute__((address_space(1))) unsigned int*)g,
      (__attribute__((address_space(3))) unsigned int*)l, 16, 0, 0);
}

// inline-asm ds_read_b128: opaque to the compiler's LDS-DMA alias tracking.
static __device__ __forceinline__ bf16x8 dsr128(unsigned byte_off){
  u32x4 r;
  asm volatile("ds_read_b128 %0, %1" : "=v"(r) : "v"(byte_off));
  return __builtin_bit_cast(bf16x8, r);
}

// ---------------- cast x -> bf16 ----------------
__global__ void cast_bf16_k(const float* __restrict__ in, ushort_t* __restrict__ out){
  long i = ((long)blockIdx.x * 256 + threadIdx.x) * 8;
  f32x4 a = *(const f32x4*)&in[i];
  f32x4 b = *(const f32x4*)&in[i + 4];
  union { ushort_t s[8]; u32x4 v; } pk;
  #pragma unroll
  for (int j = 0; j < 4; j++){ pk.s[j] = f2bf(a[j]); pk.s[j+4] = f2bf(b[j]); }
  *(u32x4*)&out[i] = pk.v;
}

// ------- transpose + cast: in[z][K][N] fp32 -> out[z][N][K] bf16, 64x64 tiles ------
__global__ void transpose_cast_k(const float* __restrict__ in, ushort_t* __restrict__ out,
                                 int K, int N){
  long zo = (long)blockIdx.z * K * N;
  in += zo; out += zo;
  __shared__ float tl[64][65];
  int n0 = blockIdx.x * 64, k0 = blockIdx.y * 64;
  int tid = threadIdx.x;           // 256
  int lr = tid >> 2;               // source row (k)
  int lv = (tid & 3) * 4;
  #pragma unroll
  for (int j = 0; j < 4; j++){
    int col = lv + j * 16;
    f32x4 v = *(const f32x4*)&in[(long)(k0 + lr) * N + n0 + col];
    tl[lr][col + 0] = v[0]; tl[lr][col + 1] = v[1];
    tl[lr][col + 2] = v[2]; tl[lr][col + 3] = v[3];
  }
  __syncthreads();
  int nl = tid >> 3;
  int kc = (tid & 7) * 8;
  #pragma unroll
  for (int it = 0; it < 2; it++){
    int n = nl + it * 32;
    union { ushort_t s[8]; u32x4 v; } pk;
    #pragma unroll
    for (int j = 0; j < 8; j++) pk.s[j] = f2bf(tl[kc + j][n]);
    *(u32x4*)&out[(long)(n0 + n) * K + k0 + kc] = pk.v;
  }
}

// ---------------- router ----------------
__global__ void router_k(const float* __restrict__ x, const float* __restrict__ rw,
                         const float* __restrict__ sgw, float* __restrict__ logits,
                         int* __restrict__ counts, int* __restrict__ lists,
                         float* __restrict__ probs, float* __restrict__ sgmul){
  int wid = threadIdx.x >> 6, lane = threadIdx.x & 63;
  int t = blockIdx.x * 4 + wid;
  const float* xr = x + (long)t * H_DIM;
  float acc[17];
  #pragma unroll
  for (int e = 0; e < 17; e++) acc[e] = 0.f;
  for (int h0 = lane * 4; h0 < H_DIM; h0 += 256){
    f32x4 xv = *(const f32x4*)&xr[h0];
    #pragma unroll
    for (int i = 0; i < 4; i++){
      float xs = xv[i];
      const float* wrow = rw + (long)(h0 + i) * NEXP;
      #pragma unroll
      for (int e = 0; e < 16; e++) acc[e] += xs * wrow[e];
      acc[16] += xs * sgw[h0 + i];
    }
  }
  #pragma unroll
  for (int e = 0; e < 17; e++)
    for (int off = 32; off >= 1; off >>= 1)
      acc[e] += __shfl_xor(acc[e], off);
  if (lane == 0){
    float* lo = logits + (long)t * NEXP;
    #pragma unroll
    for (int e = 0; e < 16; e++) lo[e] = acc[e];
    int e0 = 0;
    #pragma unroll
    for (int e = 1; e < 16; e++) if (acc[e] > acc[e0]) e0 = e;
    int e1 = (e0 == 0) ? 1 : 0;
    #pragma unroll
    for (int e = 0; e < 16; e++) if (e != e0 && acc[e] > acc[e1]) e1 = e;
    float d = acc[e1] - acc[e0];
    float ed = __expf(d);
    float p0 = 1.f / (1.f + ed);
    float p1 = ed / (1.f + ed);
    int pos0 = atomicAdd(&counts[e0], 1);
    lists[e0 * T_TOK + pos0] = t; probs[e0 * T_TOK + pos0] = p0;
    int pos1 = atomicAdd(&counts[e1], 1);
    lists[e1 * T_TOK + pos1] = t; probs[e1 * T_TOK + pos1] = p1;
    sgmul[t] = 1.f / (1.f + __expf(-acc[16]));
  }
}

// ---------------- padded prefix bases (128-aligned for 128-row tiles) ----------------
__global__ void bases_k(const int* __restrict__ counts, int* __restrict__ bases){
  if (threadIdx.x == 0){
    int r = 0;
    for (int e = 0; e < NEXP; e++){ bases[e] = r; r += (counts[e] + 127) & ~127; }
  }
}

// ---------------- SwiGLU elementwise ----------------
__global__ void swiglu_expert_k(const ushort_t* __restrict__ gu, ushort_t* __restrict__ hid){
  long qd = (long)blockIdx.x * 256 + threadIdx.x;
  long r = qd / (I_DIM / 8); int ic = (int)(qd % (I_DIM / 8)) * 8;
  const ushort_t* g = gu + r * I2_DIM + ic;
  u16x8 gv = *(const u16x8*)g;
  u16x8 uv = *(const u16x8*)(g + I_DIM);
  u16x8 ov;
  #pragma unroll
  for (int i = 0; i < 8; i++)
    ov[i] = f2bf(bf2f(uv[i]) * silu_f(bf2f(gv[i])));
  *(u16x8*)&hid[r * I_DIM + ic] = ov;
}

__global__ void swiglu_flat_k(ushort_t* __restrict__ sg, const ushort_t* __restrict__ si){
  long i = ((long)blockIdx.x * 256 + threadIdx.x) * 8;
  u16x8 g = *(const u16x8*)&sg[i];
  u16x8 s = *(const u16x8*)&si[i];
  u16x8 o;
  #pragma unroll
  for (int j = 0; j < 8; j++)
    o[j] = f2bf(bf2f(s[j]) * silu_f(bf2f(g[j])));
  *(u16x8*)&sg[i] = o;
}

// ======== 128x128 / BK=32 / 4-wave GEMM, 3-buffer counted-vmcnt, asm ds_read fragments ========
// LDS 48 KiB -> 3 blocks/CU (~12 waves/CU, m97-class TLP). Stage tile t+2 while computing t.
// Top of iter: s_waitcnt vmcnt(4) (own 4 gld16 of tile t done; t+1's in flight) -> s_barrier.
// Fragments via inline-asm ds_read_b128 (no compiler LDS-DMA alias drain), lgkmcnt(0) +
// sched_barrier(0) before the MFMA cluster (rule #18), setprio around MFMAs (T5).
template<int MODE>
static __device__ __forceinline__ void gemm3_body(
    const ushort_t* __restrict__ A, const ushort_t* __restrict__ Bt,
    const ushort_t* __restrict__ Bt2, ushort_t* __restrict__ Cb,
    int K, int lda, int ldbt, int ldc, int mb,
    const int* __restrict__ counts, const int* __restrict__ bases,
    const int* __restrict__ lists, const float* __restrict__ probs,
    const float* __restrict__ svec, float* __restrict__ outp, long bstride){
  int z = blockIdx.z;
  int cnt = T_TOK;
  const ushort_t* Ab = A;
  const ushort_t* Bb = Bt;
  long rbase = 0;
  if constexpr (MODE == 0){ if (z){ Bb = Bt2; Cb += (long)T_TOK * ldc; } }
  if constexpr (MODE == 1){ cnt = counts[z]; rbase = bases[z]; Bb += (long)z * bstride; }
  if constexpr (MODE == 2){ cnt = counts[z]; Ab += (long)bases[z] * lda; Bb += (long)z * bstride; }

  int kb = K / gridDim.y;          // MODE 3 K-split; others gridDim.y==1
  int kbase = blockIdx.y * kb;
  Ab += kbase;
  Bb += kbase;                     // Bt is [N][K], k fastest

  // bijective XCD-chunked swizzle (m204); all grids here are multiples of 8.
  int nwg = gridDim.x;
  int wgo = blockIdx.x;
  int q = nwg >> 3, r = nwg & 7;
  int xcd = wgo & 7, idx = wgo >> 3;
  int wg = (xcd < r ? xcd * (q + 1) : r * (q + 1) + (xcd - r) * q) + idx;
  int m0 = (wg % mb) * 128;
  if (m0 >= cnt) return;
  int n0 = (wg / mb) * 128;

  // 3 bufs x (A 128x32 + B 128x32) bf16 = 48 KiB
  __shared__ ushort_t lds[3 * 8192];
  unsigned lbase = (unsigned)(size_t)(__attribute__((address_space(3))) ushort_t*)lds;

  int tid = threadIdx.x;
  int lane = tid & 63;
  int wv = tid >> 6;        // 4 waves
  int wm = wv >> 1;         // 0..1 -> 64 rows
  int wn = wv & 1;          // 0..1 -> 64 cols

  // staging: wave wv stages A rows [wv*32,+32) and B rows [wv*32,+32), 2 gld16 each.
  // per gld16: 16 rows (lane>>2), 4 slots of 8 bf16 (lane&3); source slot pre-swizzled
  // (lane&3)^(row&3) so LDS[row][slot] = data[row][slot^(row&3)] with linear LDS dest.
  int srow = lane >> 2;
  int sslot = ((lane & 3) ^ (srow & 3)) * 8;
  long aoff[2], boff[2];
  #pragma unroll
  for (int c = 0; c < 2; c++){
    int mr = wv * 32 + c * 16 + srow;
    int grow;
    if constexpr (MODE == 1){
      int j = m0 + mr; if (j >= cnt) j = cnt - 1;
      grow = lists[z * T_TOK + j];
    } else {
      grow = m0 + mr;
    }
    aoff[c] = (long)grow * lda + sslot;
    boff[c] = (long)(n0 + mr) * ldbt + sslot;
  }

  auto stage = [&](int t, int buf){
    long ko = (long)t * 32;
    ushort_t* dA = lds + buf * 8192 + wv * 32 * 32;
    ushort_t* dB = dA + 4096;
    gld16(Ab + aoff[0] + ko, dA);
    gld16(Ab + aoff[1] + ko, dA + 512);
    gld16(Bb + boff[0] + ko, dB);
    gld16(Bb + boff[1] + ko, dB + 512);
  };

  f32x4 zero = {0.f, 0.f, 0.f, 0.f};
  f32x4 acc[4][4];
  #pragma unroll
  for (int i = 0; i < 4; i++)
    #pragma unroll
    for (int j = 0; j < 4; j++) acc[i][j] = zero;

  // fragment read offsets (bytes): row stride 64 B, slot = (kgroup ^ (row&3))*16
  int fr = lane & 15;
  int kg = lane >> 4;
  unsigned ps = (unsigned)((kg ^ (fr & 3)) << 4);
  unsigned aoffb = (unsigned)((wm * 64 + fr) * 64) + ps;          // A region
  unsigned boffb = 8192u + (unsigned)((wn * 64 + fr) * 64) + ps;  // B region

  int nt = kb >> 5;
  stage(0, 0);
  __builtin_amdgcn_sched_barrier(0);
  stage(1, 1);

  int rb = 0, sb = 2;
  for (int t = 0; t < nt; t++){
    if (t + 2 < nt) asm volatile("s_waitcnt vmcnt(4)" ::: "memory");
    else            asm volatile("s_waitcnt vmcnt(0)" ::: "memory");
    __builtin_amdgcn_s_barrier();
    __builtin_amdgcn_sched_barrier(0);
    unsigned bufb = lbase + (unsigned)rb * 16384u;
    bf16x8 af[4], bg[4];
    #pragma unroll
    for (int f = 0; f < 4; f++){
      af[f] = dsr128(bufb + aoffb + f * 1024u);
      bg[f] = dsr128(bufb + boffb + f * 1024u);
    }
    __builtin_amdgcn_sched_barrier(0);   // stage must not hoist above the reads
    if (t + 2 < nt) stage(t + 2, sb);
    asm volatile("s_waitcnt lgkmcnt(0)" ::: "memory");
    __builtin_amdgcn_sched_barrier(0);   // rule #18: MFMA must not hoist above lgkmcnt
    __builtin_amdgcn_s_setprio(1);
    #pragma unroll
    for (int fm = 0; fm < 4; fm++)
      #pragma unroll
      for (int fn = 0; fn < 4; fn++)
        acc[fm][fn] = __builtin_amdgcn_mfma_f32_16x16x32_bf16(af[fm], bg[fn], acc[fm][fn], 0, 0, 0);
    __builtin_amdgcn_s_setprio(0);
    rb = (rb == 2) ? 0 : rb + 1;
    sb = (sb == 2) ? 0 : sb + 1;
  }

  int colb = n0 + wn * 64 + (lane & 15);
  int rowb = m0 + wm * 64 + (lane >> 4) * 4;
  #pragma unroll
  for (int fm = 0; fm < 4; fm++){
    #pragma unroll
    for (int fn = 0; fn < 4; fn++){
      f32x4 v = acc[fm][fn];
      int col = colb + fn * 16;
      #pragma unroll
      for (int rr = 0; rr < 4; rr++){
        int m = rowb + fm * 16 + rr;
        if constexpr (MODE == 0){
          Cb[(long)m * ldc + col] = f2bf(v[rr]);
        } else if constexpr (MODE == 1){
          if (m < cnt) Cb[(rbase + m) * (long)ldc + col] = f2bf(v[rr]);
        } else if constexpr (MODE == 2){
          if (m < cnt){
            int tok = lists[z * T_TOK + m];
            float pp = probs[z * T_TOK + m];
            atomicAdd(outp + (long)tok * ldc + col, pp * v[rr]);
          }
        } else {
          atomicAdd(outp + (long)m * ldc + col, svec[m] * v[rr]);
        }
      }
    }
  }
}

// distinct names so rocprof top-k localizes cost per mode
#define GEMM_ARGS const ushort_t* A, const ushort_t* Bt, const ushort_t* Bt2, ushort_t* Cb, \
    int K, int lda, int ldbt, int ldc, int mb, const int* counts, const int* bases, \
    const int* lists, const float* probs, const float* svec, float* outp, long bstride
#define GEMM_PASS A, Bt, Bt2, Cb, K, lda, ldbt, ldc, mb, counts, bases, lists, probs, svec, outp, bstride

__global__ __launch_bounds__(256) void g_shared_gi(GEMM_ARGS){ gemm3_body<0>(GEMM_PASS); }
__global__ __launch_bounds__(256) void g_shared_out(GEMM_ARGS){ gemm3_body<3>(GEMM_PASS); }
__global__ __launch_bounds__(256) void g_expert_gu(GEMM_ARGS){ gemm3_body<1>(GEMM_PASS); }
__global__ __launch_bounds__(256) void g_expert_out(GEMM_ARGS){ gemm3_body<2>(GEMM_PASS); }

extern "C" void kernel_launch(void* const* d_in, const int* in_sizes, int n_in,
                              void* d_out, int out_size, void* d_ws, size_t ws_size,
                              hipStream_t stream){
  const float* x    = (const float*)d_in[0];
  const float* rw   = (const float*)d_in[1];
  const float* wgu  = (const float*)d_in[2];
  const float* wout = (const float*)d_in[3];
  const float* wsg  = (const float*)d_in[4];
  const float* wsi  = (const float*)d_in[5];
  const float* wso  = (const float*)d_in[6];
  const float* sgw  = (const float*)d_in[7];

  float* out = (float*)d_out;
  float* logits = out + (size_t)T_TOK * H_DIM;

  char* w = (char*)d_ws;
  auto alloc = [&](size_t b){ char* p = w; w += (b + 255) & ~(size_t)255; return p; };
  ushort_t* xb     = (ushort_t*)alloc((size_t)T_TOK * H_DIM * 2);
  ushort_t* wgu_t  = (ushort_t*)alloc((size_t)NEXP * I2_DIM * H_DIM * 2);
  ushort_t* wout_t = (ushort_t*)alloc((size_t)NEXP * H_DIM * I_DIM * 2);
  ushort_t* wsg_t  = (ushort_t*)alloc((size_t)IS_DIM * H_DIM * 2);
  ushort_t* wsi_t  = (ushort_t*)alloc((size_t)IS_DIM * H_DIM * 2);
  ushort_t* wso_t  = (ushort_t*)alloc((size_t)H_DIM * IS_DIM * 2);
  ushort_t* sgr    = (ushort_t*)alloc((size_t)2 * T_TOK * IS_DIM * 2);
  ushort_t* sir    = sgr + (size_t)T_TOK * IS_DIM;
  ushort_t* gu     = (ushort_t*)alloc((size_t)MAXROWS * I2_DIM * 2);
  ushort_t* hid    = (ushort_t*)alloc((size_t)MAXROWS * I_DIM * 2);
  int*   counts = (int*)alloc(64);
  int*   bases  = (int*)alloc(64);
  int*   lists  = (int*)alloc((size_t)NEXP * T_TOK * 4);
  float* probs  = (float*)alloc((size_t)NEXP * T_TOK * 4);
  float* sgmul  = (float*)alloc((size_t)T_TOK * 4);

  hipMemsetAsync(counts, 0, 64, stream);
  hipMemsetAsync(out, 0, (size_t)T_TOK * H_DIM * sizeof(float), stream);

  cast_bf16_k<<<2048, 256, 0, stream>>>(x, xb);
  transpose_cast_k<<<dim3(I2_DIM/64, H_DIM/64, NEXP), 256, 0, stream>>>(wgu, wgu_t, H_DIM, I2_DIM);
  transpose_cast_k<<<dim3(H_DIM/64, I_DIM/64, NEXP), 256, 0, stream>>>(wout, wout_t, I_DIM, H_DIM);
  transpose_cast_k<<<dim3(IS_DIM/64, H_DIM/64, 1), 256, 0, stream>>>(wsg, wsg_t, H_DIM, IS_DIM);
  transpose_cast_k<<<dim3(IS_DIM/64, H_DIM/64, 1), 256, 0, stream>>>(wsi, wsi_t, H_DIM, IS_DIM);
  transpose_cast_k<<<dim3(H_DIM/64, IS_DIM/64, 1), 256, 0, stream>>>(wso, wso_t, IS_DIM, H_DIM);

  router_k<<<512, 256, 0, stream>>>(x, rw, sgw, logits, counts, lists, probs, sgmul);
  bases_k<<<1, 64, 0, stream>>>(counts, bases);

  // shared expert: gate & inter in one launch (z selects weight)
  g_shared_gi<<<dim3((T_TOK/128) * (IS_DIM/128), 1, 2), 256, 0, stream>>>(
      xb, wsg_t, wsi_t, sgr, H_DIM, H_DIM, H_DIM, IS_DIM, T_TOK/128,
      nullptr, nullptr, nullptr, nullptr, nullptr, nullptr, 0);
  swiglu_flat_k<<<(T_TOK * (IS_DIM/8)) / 256, 256, 0, stream>>>(sgr, sir);
  // shared out-projection, K-split x4, atomic accumulate into zeroed out
  g_shared_out<<<dim3((T_TOK/128) * (H_DIM/128), 4, 1), 256, 0, stream>>>(
      sgr, wso_t, nullptr, nullptr, IS_DIM, IS_DIM, IS_DIM, H_DIM, T_TOK/128,
      nullptr, nullptr, nullptr, nullptr, sgmul, out, 0);

  // sparse routed experts (atomic add on top of shared output)
  g_expert_gu<<<dim3((T_TOK/128) * (I2_DIM/128), 1, NEXP), 256, 0, stream>>>(
      xb, wgu_t, nullptr, gu, H_DIM, H_DIM, H_DIM, I2_DIM, T_TOK/128,
      counts, bases, lists, probs, nullptr, nullptr, (long)I2_DIM * H_DIM);
  swiglu_expert_k<<<((long)MAXROWS * (I_DIM/8)) / 256, 256, 0, stream>>>(gu, hid);
  g_expert_out<<<dim3((T_TOK/128) * (H_DIM/128), 1, NEXP), 256, 0, stream>>>(
      hid, wout_t, nullptr, nullptr, I_DIM, I_DIM, I_DIM, H_DIM, T_TOK/128,
      counts, bases, lists, probs, nullptr, out, (long)I_DIM * H_DIM);

  (void)in_sizes; (void)n_in; (void)out_size; (void)ws_size;
}